// Round 12
// baseline (724.394 us; speedup 1.0000x reference)
//
#include <hip/hip_runtime.h>
#include <hip/hip_bf16.h>
#include <math.h>

#define T_SEQ  180
#define LATENT 128
#define HIDDEN 256

typedef __attribute__((ext_vector_type(8))) short  short8;   // 8 x bf16 (4 VGPRs)
typedef __attribute__((ext_vector_type(4))) float  floatx4;  // MFMA acc

// ---- d_ws layout (ushort units) ----
#define WHH_US 196608   // fc_w pack starts here

// ---- dynamic LDS layout (bytes) ----
// [0,      131072) : w_hh n-gate frags s=4,5: ((wv*2+s2)*8+kc)*1024 B
// [131072, 147968) : h_lds 32 rows x 264 ushorts
// [147968, 151040) : obufw [3][8][16][2] float (per-wave proj partials)
// [151040, 163328) : LUTs: sigmoid[768] + tanh[768], float2(y, dy), x in [-12,12) step 1/32
#define HLDS_OFF   131072
#define OBUF_OFF   147968
#define LUT_OFF    151040
#define SMEM_BYTES 163328

__device__ __forceinline__ unsigned short f2bf(float f) {
    unsigned int u = __float_as_uint(f);
    u += 0x7fffu + ((u >> 16) & 1u);      // round-to-nearest-even
    return (unsigned short)(u >> 16);
}

__device__ __forceinline__ float sigmoid_ref(float x) {
    return 1.0f / (1.0f + __expf(-x));
}
__device__ __forceinline__ float tanh_ref(float x) {
    return 1.0f - 2.0f / (1.0f + __expf(2.0f * x));
}

// Pack w_hh [768,256] fp32 row-major -> bf16 MFMA B-fragments.
__global__ void pack_whh(const float* __restrict__ whh, unsigned short* __restrict__ dst) {
    int tid  = blockIdx.x * blockDim.x + threadIdx.x;  // 24576 threads
    int lane = tid & 63;
    int frag = tid >> 6;                               // 0..383
    int kc   = frag & 7;
    int sub  = (frag >> 3) % 6;
    int w    = frag / 48;
    int g = sub >> 1, cs = sub & 1;
    int col  = w * 32 + cs * 16 + (lane & 15);
    int jout = g * 256 + col;
    int k0   = kc * 32 + ((lane >> 4) << 3);
    const float* src = whh + jout * 256 + k0;
    unsigned int u[4];
#pragma unroll
    for (int j = 0; j < 4; ++j)
        u[j] = (unsigned int)f2bf(src[2 * j]) | ((unsigned int)f2bf(src[2 * j + 1]) << 16);
    *(uint4*)(dst + frag * 512 + lane * 8) = make_uint4(u[0], u[1], u[2], u[3]);
}

// Pack fc_w [256,128] fp32 row-major -> bf16 MFMA B-fragments.
__global__ void pack_fcw(const float* __restrict__ fcw, unsigned short* __restrict__ dst) {
    int tid  = blockIdx.x * blockDim.x + threadIdx.x;  // 4096 threads
    int lane = tid & 63;
    int frag = tid >> 6;                               // 0..63
    int kc   = frag & 3;
    int cs   = (frag >> 2) & 1;
    int w    = frag >> 3;
    int col  = w * 32 + cs * 16 + (lane & 15);
    int k0   = kc * 32 + ((lane >> 4) << 3);
    const float* src = fcw + col * 128 + k0;
    unsigned int u[4];
#pragma unroll
    for (int j = 0; j < 4; ++j)
        u[j] = (unsigned int)f2bf(src[2 * j]) | ((unsigned int)f2bf(src[2 * j + 1]) << 16);
    *(uint4*)(dst + frag * 512 + lane * 8) = make_uint4(u[0], u[1], u[2], u[3]);
}

// Persistent GRU: 256 blocks x 512 threads, 32 rows/block, wave owns 32 cols.
// r9 base (best, 587us): 32 weight frags in regs, n-gate (s=4,5) in LDS,
// anti-phase grp=(wv>>2)&1, 2 slots/step. r12: transcendental diet --
// step = MFMA(3802cyc) + VALU(4040cyc) serialized (model exact vs r9 counters);
// 96 quarter-rate exp/rcp per wave-step are ~1536 cyc of the VALU phase.
// sigma/tanh via LDS lerp-LUT (768 x float2, step 1/32, err <= 1e-4) cuts the
// gate element cost from ~113 to ~46 cyc. Register law (r4/r5): do not grow
// weight regs past 32 frags.
__global__ __launch_bounds__(512, 2) void gru_main(
    const float* __restrict__ z,
    const float* __restrict__ fc_b,
    const float* __restrict__ b_ih,
    const float* __restrict__ b_hh,
    const float* __restrict__ out_w,
    const float* __restrict__ out_b,
    const unsigned short* __restrict__ wpack,
    float* __restrict__ out)
{
    extern __shared__ unsigned char smem[];
    unsigned short* wlds  = (unsigned short*)smem;               // s=4,5 frags
    unsigned short* h_lds = (unsigned short*)(smem + HLDS_OFF);
    float*          obufw = (float*)(smem + OBUF_OFF);           // [3][8][16][2]
    float2*         lut   = (float2*)(smem + LUT_OFF);           // [768 sig][768 tanh]

    const int tid  = threadIdx.x;
    const int lane = tid & 63;
    const int wv   = tid >> 6;
    const int grp  = (wv >> 2) & 1;  // r9 anti-phase predicate (best variant)
    const int l15  = lane & 15;
    const int qd   = lane >> 4;
    const int rb   = blockIdx.x * 32;

    // ---- build sigma/tanh lerp LUTs (once per block) ----
    for (int k = tid; k < 768; k += 512) {
        float x0 = -12.0f + k * 0.03125f;
        float x1 = x0 + 0.03125f;
        float s0 = sigmoid_ref(x0), s1 = sigmoid_ref(x1);
        lut[k] = make_float2(s0, s1 - s0);
        float t0 = tanh_ref(x0), t1 = tanh_ref(x1);
        lut[768 + k] = make_float2(t0, t1 - t0);
    }

    // ---- stage n-gate weight frags (s=4,5) into LDS (16 KB per wave) ----
#pragma unroll
    for (int s2 = 0; s2 < 2; ++s2)
#pragma unroll
        for (int kc = 0; kc < 8; ++kc) {
            int gfrag = (wv * 6 + 4 + s2) * 8 + kc;
            uint4 v = *(const uint4*)(wpack + gfrag * 512 + lane * 8);
            *(uint4*)(wlds + (((wv * 2 + s2) * 8 + kc) << 9) + lane * 8) = v;
        }

    // ---- r,z-gate weight frags into registers (32 frags = 128 VGPRs) ----
    short8 wreg[32];
#pragma unroll
    for (int s = 0; s < 4; ++s)
#pragma unroll
        for (int kc = 0; kc < 8; ++kc)
            wreg[s * 8 + kc] = ((const short8*)wpack)[((wv * 6 + s) * 8 + kc) * 64 + lane];

    // ---- stage z tile into h_lds ----
    {
        int row = tid >> 4;
        int seg = tid & 15;
        const float* zp = z + (size_t)(rb + row) * LATENT + seg * 8;
        unsigned int u[4];
#pragma unroll
        for (int j = 0; j < 4; ++j)
            u[j] = (unsigned int)f2bf(zp[2 * j]) | ((unsigned int)f2bf(zp[2 * j + 1]) << 16);
        *(uint4*)&h_lds[row * 264 + seg * 8] = make_uint4(u[0], u[1], u[2], u[3]);
    }

    // ---- per-lane constants ----
    float cb[2][2], bhn[2], bin[2], fcb[2];
#pragma unroll
    for (int cs = 0; cs < 2; ++cs) {
        int col = wv * 32 + cs * 16 + l15;
        cb[0][cs] = b_ih[col]       + b_hh[col];
        cb[1][cs] = b_ih[256 + col] + b_hh[256 + col];
        bin[cs]   = b_ih[512 + col];
        bhn[cs]   = b_hh[512 + col];
        fcb[cs]   = fc_b[col];
    }
    float ob = (tid < 64) ? out_b[tid & 1] : 0.0f;

    // projection B-frag: B[k][n], k = wv*32 + qd*8 + j, n = l15 (0,1 used)
    short8 bproj;
    {
        int k0 = wv * 32 + qd * 8;
#pragma unroll
        for (int j = 0; j < 8; ++j) {
            float v = (l15 == 0) ? out_w[k0 + j] : ((l15 == 1) ? out_w[256 + k0 + j] : 0.0f);
            bproj[j] = (short)f2bf(v);
        }
    }

    __syncthreads();   // LUTs + weights + z staged

    // ---- LUT lookups: idx = clamp((x+12)*32, 0, 766.999), lerp ----
    auto lut_sig = [&](float x) -> float {
        float p = __builtin_fmaf(x, 32.0f, 384.0f);
        p = fminf(fmaxf(p, 0.0f), 766.99f);
        int i = (int)p;
        float f = p - (float)i;
        float2 e = lut[i];
        return __builtin_fmaf(f, e.y, e.x);
    };
    auto lut_th = [&](float x) -> float {
        float p = __builtin_fmaf(x, 32.0f, 384.0f);
        p = fminf(fmaxf(p, 0.0f), 766.99f);
        int i = (int)p;
        float f = p - (float)i;
        float2 e = lut[768 + i];
        return __builtin_fmaf(f, e.y, e.x);
    };

    // ---- h0 = tanh(z @ fc_w^T + fc_b) ----
    floatx4 a0f[2][2];
#pragma unroll
    for (int rt = 0; rt < 2; ++rt)
#pragma unroll
        for (int cs = 0; cs < 2; ++cs)
            a0f[rt][cs] = (floatx4){0.f, 0.f, 0.f, 0.f};
#pragma unroll
    for (int kc = 0; kc < 4; ++kc) {
        short8 afr0 = *(const short8*)&h_lds[(0  + l15) * 264 + kc * 32 + qd * 8];
        short8 afr1 = *(const short8*)&h_lds[(16 + l15) * 264 + kc * 32 + qd * 8];
#pragma unroll
        for (int cs = 0; cs < 2; ++cs) {
            short8 bfr = ((const short8*)wpack)[(size_t)(WHH_US / 8) + ((wv * 2 + cs) * 4 + kc) * 64 + lane];
            a0f[0][cs] = __builtin_amdgcn_mfma_f32_16x16x32_bf16(afr0, bfr, a0f[0][cs], 0, 0, 0);
            a0f[1][cs] = __builtin_amdgcn_mfma_f32_16x16x32_bf16(afr1, bfr, a0f[1][cs], 0, 0, 0);
        }
    }

    float hm0[2][4], hm1[2][4];
#pragma unroll
    for (int cs = 0; cs < 2; ++cs)
#pragma unroll
        for (int r = 0; r < 4; ++r) {
            hm0[cs][r] = lut_th(a0f[0][cs][r] + fcb[cs]);
            hm1[cs][r] = lut_th(a0f[1][cs][r] + fcb[cs]);
        }

    __syncthreads();   // done reading z
#pragma unroll
    for (int cs = 0; cs < 2; ++cs)
#pragma unroll
        for (int r = 0; r < 4; ++r) {
            h_lds[(0  + qd * 4 + r) * 264 + wv * 32 + cs * 16 + l15] = f2bf(hm0[cs][r]);
            h_lds[(16 + qd * 4 + r) * 264 + wv * 32 + cs * 16 + l15] = f2bf(hm1[cs][r]);
        }
    __syncthreads();

    // one r-unit of gate nonlinearity + h update + LDS writeback (both cs)
    auto gate_unit = [&](floatx4* a, float (*hmH)[4], int rowbase, int r) {
        float hv[2];
#pragma unroll
        for (int cs = 0; cs < 2; ++cs) {
            float gr = lut_sig(a[cs][r]);
            float gz = lut_sig(a[2 + cs][r]);
            float gn = lut_th(bin[cs] + gr * a[4 + cs][r]);
            float h  = gn + gz * (hmH[cs][r] - gn);
            hmH[cs][r] = h;
            hv[cs] = h;
        }
        __hip_bfloat162 pk = __float22bfloat162_rn(make_float2(hv[0], hv[1]));
        union { __hip_bfloat16 b; unsigned short u; } cu0, cu1;
        cu0.b = pk.x; cu1.b = pk.y;
        int rowoff = (rowbase + qd * 4 + r) * 264 + wv * 32 + l15;
        h_lds[rowoff]      = cu0.u;
        h_lds[rowoff + 16] = cu1.u;
    };

    // identity-gate init: sigma(40->clamped)=1 => slot X t=0 rewrites h0 unchanged
    floatx4 acc1[6];
#pragma unroll
    for (int s = 0; s < 6; ++s)
        acc1[s] = (s == 2 || s == 3) ? (floatx4){40.f, 40.f, 40.f, 40.f}
                                     : (floatx4){0.f, 0.f, 0.f, 0.f};

    floatx4 acc0[6];

    // ---- 180 steps, 2 anti-phased slots each ----
#pragma unroll 1
    for (int t = 0; t < T_SEQ; ++t) {
        // ======== SLOT X: MFMA rows0-15 (state t-1) ; gates rows16-31 -> state t ========
        auto mfmaX = [&]() {
#pragma unroll
            for (int s = 0; s < 6; ++s) {
                float b = (s < 4) ? cb[s >> 1][s & 1] : bhn[s & 1];
                acc0[s] = (floatx4){b, b, b, b};
            }
#pragma unroll
            for (int kc = 0; kc < 8; ++kc) {
                short8 afr = *(const short8*)&h_lds[l15 * 264 + kc * 32 + qd * 8];
#pragma unroll
                for (int s = 0; s < 4; ++s)
                    acc0[s] = __builtin_amdgcn_mfma_f32_16x16x32_bf16(afr, wreg[s * 8 + kc], acc0[s], 0, 0, 0);
                short8 b4 = *(const short8*)&wlds[(((wv * 2 + 0) * 8 + kc) << 9) + lane * 8];
                short8 b5 = *(const short8*)&wlds[(((wv * 2 + 1) * 8 + kc) << 9) + lane * 8];
                acc0[4] = __builtin_amdgcn_mfma_f32_16x16x32_bf16(afr, b4, acc0[4], 0, 0, 0);
                acc0[5] = __builtin_amdgcn_mfma_f32_16x16x32_bf16(afr, b5, acc0[5], 0, 0, 0);
            }
        };
        auto gatesX = [&]() {
#pragma unroll
            for (int r = 0; r < 4; ++r)
                gate_unit(acc1, hm1, 16, r);      // rows16-31 -> state t
        };
        if (grp == 0) { mfmaX(); gatesX(); }       // wave-uniform branch
        else          { gatesX(); mfmaX(); }       // SIMD partner opposite order
        floatx4 pj0 = (floatx4){0.f, 0.f, 0.f, 0.f};
        {
            short8 afrp = *(const short8*)&h_lds[l15 * 264 + wv * 32 + qd * 8];
            pj0 = __builtin_amdgcn_mfma_f32_16x16x32_bf16(afrp, bproj, pj0, 0, 0, 0);
        }
        if (t >= 2 && tid < 32) {                 // flush bufB: out idx t-2, rows16-31
            int rl = tid >> 1, o = tid & 1;
            float s = ob;
#pragma unroll
            for (int w2 = 0; w2 < 8; ++w2) s += obufw[256 + w2 * 32 + rl * 2 + o];
            out[(size_t)(rb + 16 + rl) * (T_SEQ * 2) + (t - 2) * 2 + o] = s;
        }
        if (t >= 1 && l15 < 2) {                  // per-wave store, no atomics
#pragma unroll
            for (int r = 0; r < 4; ++r)
                obufw[wv * 32 + (qd * 4 + r) * 2 + l15] = pj0[r];
        }
        __syncthreads();

        // ======== SLOT Y: MFMA rows16-31 (state t) ; gates rows0-15 -> state t ========
        auto mfmaY = [&]() {
#pragma unroll
            for (int s = 0; s < 6; ++s) {
                float b = (s < 4) ? cb[s >> 1][s & 1] : bhn[s & 1];
                acc1[s] = (floatx4){b, b, b, b};
            }
#pragma unroll
            for (int kc = 0; kc < 8; ++kc) {
                short8 afr = *(const short8*)&h_lds[(16 + l15) * 264 + kc * 32 + qd * 8];
#pragma unroll
                for (int s = 0; s < 4; ++s)
                    acc1[s] = __builtin_amdgcn_mfma_f32_16x16x32_bf16(afr, wreg[s * 8 + kc], acc1[s], 0, 0, 0);
                short8 b4 = *(const short8*)&wlds[(((wv * 2 + 0) * 8 + kc) << 9) + lane * 8];
                short8 b5 = *(const short8*)&wlds[(((wv * 2 + 1) * 8 + kc) << 9) + lane * 8];
                acc1[4] = __builtin_amdgcn_mfma_f32_16x16x32_bf16(afr, b4, acc1[4], 0, 0, 0);
                acc1[5] = __builtin_amdgcn_mfma_f32_16x16x32_bf16(afr, b5, acc1[5], 0, 0, 0);
            }
        };
        auto gatesY = [&]() {
#pragma unroll
            for (int r = 0; r < 4; ++r)
                gate_unit(acc0, hm0, 0, r);       // rows0-15 -> state t
        };
        if (grp == 0) { mfmaY(); gatesY(); }
        else          { gatesY(); mfmaY(); }
        floatx4 pj1 = (floatx4){0.f, 0.f, 0.f, 0.f};
        {
            short8 afrp = *(const short8*)&h_lds[(16 + l15) * 264 + wv * 32 + qd * 8];
            pj1 = __builtin_amdgcn_mfma_f32_16x16x32_bf16(afrp, bproj, pj1, 0, 0, 0);
        }
        if (t >= 1 && tid < 32) {                 // flush bufA: out idx t-1, rows0-15
            int rl = tid >> 1, o = tid & 1;
            float s = ob;
#pragma unroll
            for (int w2 = 0; w2 < 8; ++w2) s += obufw[w2 * 32 + rl * 2 + o];
            out[(size_t)(rb + rl) * (T_SEQ * 2) + (t - 1) * 2 + o] = s;
        }
        if (t >= 1 && l15 < 2) {
#pragma unroll
            for (int r = 0; r < 4; ++r)
                obufw[256 + wv * 32 + (qd * 4 + r) * 2 + l15] = pj1[r];
        }
        __syncthreads();
    }

    // ---- epilogue: finish final rows16-31 state, project final state (out idx 179) ----
#pragma unroll
    for (int r = 0; r < 4; ++r)
        gate_unit(acc1, hm1, 16, r);              // rows16-31 final state
    if (tid < 32) {                               // flush bufB: out idx 178, rows16-31
        int rl = tid >> 1, o = tid & 1;
        float s = ob;
#pragma unroll
        for (int w2 = 0; w2 < 8; ++w2) s += obufw[256 + w2 * 32 + rl * 2 + o];
        out[(size_t)(rb + 16 + rl) * (T_SEQ * 2) + 178 * 2 + o] = s;
    }
    {   // proj of final state rows0-15 (written in last slot Y, barrier passed)
        short8 afrp = *(const short8*)&h_lds[l15 * 264 + wv * 32 + qd * 8];
        floatx4 pj = (floatx4){0.f, 0.f, 0.f, 0.f};
        pj = __builtin_amdgcn_mfma_f32_16x16x32_bf16(afrp, bproj, pj, 0, 0, 0);
        if (l15 < 2)
#pragma unroll
            for (int r = 0; r < 4; ++r)
                obufw[wv * 32 + (qd * 4 + r) * 2 + l15] = pj[r];
    }
    __syncthreads();
    {   // proj of final state rows16-31 (written by gate_units above, barrier passed)
        short8 afrp = *(const short8*)&h_lds[(16 + l15) * 264 + wv * 32 + qd * 8];
        floatx4 pj = (floatx4){0.f, 0.f, 0.f, 0.f};
        pj = __builtin_amdgcn_mfma_f32_16x16x32_bf16(afrp, bproj, pj, 0, 0, 0);
        if (l15 < 2)
#pragma unroll
            for (int r = 0; r < 4; ++r)
                obufw[512 + wv * 32 + (qd * 4 + r) * 2 + l15] = pj[r];
    }
    if (tid < 32) {                               // flush bufA: out idx 179, rows0-15
        int rl = tid >> 1, o = tid & 1;
        float s = ob;
#pragma unroll
        for (int w2 = 0; w2 < 8; ++w2) s += obufw[w2 * 32 + rl * 2 + o];
        out[(size_t)(rb + rl) * (T_SEQ * 2) + 179 * 2 + o] = s;
    }
    __syncthreads();
    if (tid < 32) {                               // flush bufC: out idx 179, rows16-31
        int rl = tid >> 1, o = tid & 1;
        float s = ob;
#pragma unroll
        for (int w2 = 0; w2 < 8; ++w2) s += obufw[512 + w2 * 32 + rl * 2 + o];
        out[(size_t)(rb + 16 + rl) * (T_SEQ * 2) + 179 * 2 + o] = s;
    }
}

extern "C" void kernel_launch(void* const* d_in, const int* in_sizes, int n_in,
                              void* d_out, int out_size, void* d_ws, size_t ws_size,
                              hipStream_t stream) {
    const float* z     = (const float*)d_in[0];
    const float* fc_w  = (const float*)d_in[1];
    const float* fc_b  = (const float*)d_in[2];
    // d_in[3] = w_ih : unused (GRU input is all-zeros, gi = b_ih)
    const float* b_ih  = (const float*)d_in[4];
    const float* w_hh  = (const float*)d_in[5];
    const float* b_hh  = (const float*)d_in[6];
    const float* out_w = (const float*)d_in[7];
    const float* out_b = (const float*)d_in[8];
    float* out = (float*)d_out;
    unsigned short* wpack = (unsigned short*)d_ws;

    hipFuncSetAttribute((const void*)gru_main,
                        hipFuncAttributeMaxDynamicSharedMemorySize, SMEM_BYTES);

    pack_whh<<<96, 256, 0, stream>>>(w_hh, wpack);
    pack_fcw<<<16, 256, 0, stream>>>(fc_w, wpack + WHH_US);
    gru_main<<<256, 512, SMEM_BYTES, stream>>>(z, fc_b, b_ih, b_hh, out_w, out_b, wpack, out);
}

// Round 13
// 603.351 us; speedup vs baseline: 1.2006x; 1.2006x over previous
//
#include <hip/hip_runtime.h>
#include <hip/hip_bf16.h>

#define T_SEQ  180
#define LATENT 128
#define HIDDEN 256

typedef __attribute__((ext_vector_type(8))) short  short8;   // 8 x bf16 (4 VGPRs)
typedef __attribute__((ext_vector_type(4))) float  floatx4;  // f32 MFMA acc
typedef __attribute__((ext_vector_type(4))) int    intx4;    // i8 frag / i32 acc

// ---- d_ws layout (BYTES) ----
// [0,      196608) : w_hh i8 frags: frag=(wv*6+(g*2+cs))*4+kc, 1024 B each (lane*16)
// [196608, 262144) : fc_w bf16 frags (r9 layout): frag=(wv*2+cs)*4+kc, 1024 B each
// [262144, 265216) : scales float[768] = max|w_hh row j| per output unit
#define WQ_OFF   0
#define FCW_OFF  196608
#define SC_OFF   262144

// ---- dynamic LDS layout (bytes) ----
// [0,     16896) : h_lds bf16, 32 rows x 264 ushorts (z staging + proj operand)
// [16896, 25600) : h8 i8,      32 rows x 272 bytes   (gate-MFMA A operand)
// [25600, 28672) : obufw [3][8][16][2] float (per-wave proj partials)
#define H8_OFF     16896
#define OBUF_OFF   25600
#define SMEM_BYTES 28672

__device__ __forceinline__ unsigned short f2bf(float f) {
    unsigned int u = __float_as_uint(f);
    u += 0x7fffu + ((u >> 16) & 1u);      // round-to-nearest-even
    return (unsigned short)(u >> 16);
}

__device__ __forceinline__ float sigmoid_fast(float x) {
    return __builtin_amdgcn_rcpf(1.0f + __expf(-x));
}
__device__ __forceinline__ float tanh_fast(float x) {
    // tanh(x) = 1 - 2/(e^{2x}+1); overflow-safe
    return 1.0f - 2.0f * __builtin_amdgcn_rcpf(1.0f + __expf(2.0f * x));
}

// Per-output-unit scales: one wave per row j of w_hh (768 rows x 256).
__global__ void pack_scales(const float* __restrict__ whh, float* __restrict__ scales) {
    int wid  = blockIdx.x * 4 + (threadIdx.x >> 6);   // 0..767
    int lane = threadIdx.x & 63;
    const float* src = whh + (size_t)wid * 256 + lane * 4;
    float m = 0.0f;
#pragma unroll
    for (int j = 0; j < 4; ++j) m = fmaxf(m, fabsf(src[j]));
#pragma unroll
    for (int d = 1; d < 64; d <<= 1) m = fmaxf(m, __shfl_xor(m, d, 64));
    if (lane == 0) scales[wid] = m;
}

// Pack w_hh [768,256] fp32 -> i8 MFMA B-frags for 16x16x64.
// B[k][n]: n = lane&15, k = kc*64 + (lane>>4)*16 + j (16 consecutive bytes).
__global__ void pack_whh_i8(const float* __restrict__ whh, const float* __restrict__ scales,
                            signed char* __restrict__ dst) {
    int tid  = blockIdx.x * blockDim.x + threadIdx.x;  // 12288 threads
    int lane = tid & 63;
    int frag = tid >> 6;                               // 0..191
    int kc   = frag & 3;
    int sub  = (frag >> 2) % 6;
    int w    = frag / 24;
    int g = sub >> 1, cs = sub & 1;
    int col  = w * 32 + cs * 16 + (lane & 15);
    int jout = g * 256 + col;
    int k0   = kc * 64 + ((lane >> 4) << 4);
    const float* src = whh + (size_t)jout * 256 + k0;
    float inv = 127.0f / scales[jout];
    signed char q[16];
#pragma unroll
    for (int j = 0; j < 16; ++j) {
        float v = __builtin_rintf(src[j] * inv);
        v = fminf(fmaxf(v, -127.0f), 127.0f);
        q[j] = (signed char)(int)v;
    }
    *(intx4*)(dst + (size_t)frag * 1024 + lane * 16) = *(intx4*)q;
}

// Pack fc_w [256,128] fp32 -> bf16 16x16x32 B-frags (r9 layout, K=128 kc 0..3).
__global__ void pack_fcw(const float* __restrict__ fcw, unsigned short* __restrict__ dst) {
    int tid  = blockIdx.x * blockDim.x + threadIdx.x;  // 4096 threads
    int lane = tid & 63;
    int frag = tid >> 6;                               // 0..63
    int kc   = frag & 3;
    int cs   = (frag >> 2) & 1;
    int w    = frag >> 3;
    int col  = w * 32 + cs * 16 + (lane & 15);
    int k0   = kc * 32 + ((lane >> 4) << 3);
    const float* src = fcw + col * 128 + k0;
    unsigned int u[4];
#pragma unroll
    for (int j = 0; j < 4; ++j)
        u[j] = (unsigned int)f2bf(src[2 * j]) | ((unsigned int)f2bf(src[2 * j + 1]) << 16);
    *(uint4*)(dst + frag * 512 + lane * 8) = make_uint4(u[0], u[1], u[2], u[3]);
}

// Persistent GRU: 256 blocks x 512 threads, 32 rows/block, wave owns 32 cols.
// r13: gate matmuls in i8 (mfma_i32_16x16x64_i8, 2x rate + 2x K => matrix
// phase ~1050 vs 3400 cyc/SIMD). ALL 3 gates' weights in registers (24 i8
// frags = 96 VGPR -- r4/r5 law respected). h kept twice: i8 (gate A-operand,
// global scale 127, |h|<=1 exact bound) + bf16 (projection, out_w precision).
// Per-column weight scales; dequant folds into one fma per gate.
// r9's anti-phase + 2-slot + proj/obuf machinery retained unchanged.
__global__ __launch_bounds__(512, 2) void gru_main(
    const float* __restrict__ z,
    const float* __restrict__ fc_b,
    const float* __restrict__ b_ih,
    const float* __restrict__ b_hh,
    const float* __restrict__ out_w,
    const float* __restrict__ out_b,
    const unsigned char* __restrict__ ws,
    float* __restrict__ out)
{
    extern __shared__ unsigned char smem[];
    unsigned short* h_lds = (unsigned short*)smem;               // bf16 h (proj)
    signed char*    h8    = (signed char*)(smem + H8_OFF);       // i8 h (gates)
    float*          obufw = (float*)(smem + OBUF_OFF);           // [3][8][16][2]

    const int tid  = threadIdx.x;
    const int lane = tid & 63;
    const int wv   = tid >> 6;
    const int grp  = (wv >> 2) & 1;  // r9 anti-phase predicate (best variant)
    const int l15  = lane & 15;
    const int qd   = lane >> 4;
    const int rb   = blockIdx.x * 32;

    // ---- all 3 gates' i8 weight frags into registers (24 frags = 96 VGPRs) ----
    intx4 wq[24];
#pragma unroll
    for (int sub = 0; sub < 6; ++sub)
#pragma unroll
        for (int kc = 0; kc < 4; ++kc)
            wq[sub * 4 + kc] = *(const intx4*)(ws + WQ_OFF
                                + (size_t)((wv * 6 + sub) * 4 + kc) * 1024 + lane * 16);

    // ---- stage z tile (bf16) into h_lds ----
    {
        int row = tid >> 4;
        int seg = tid & 15;
        const float* zp = z + (size_t)(rb + row) * LATENT + seg * 8;
        unsigned int u[4];
#pragma unroll
        for (int j = 0; j < 4; ++j)
            u[j] = (unsigned int)f2bf(zp[2 * j]) | ((unsigned int)f2bf(zp[2 * j + 1]) << 16);
        *(uint4*)&h_lds[row * 264 + seg * 8] = make_uint4(u[0], u[1], u[2], u[3]);
    }

    // ---- per-lane constants ----
    const float* scales = (const float*)(ws + SC_OFF);
    float cb[2][2], bhn[2], bin[2], fcb[2], scq[3][2];
#pragma unroll
    for (int cs = 0; cs < 2; ++cs) {
        int col = wv * 32 + cs * 16 + l15;
        cb[0][cs] = b_ih[col]       + b_hh[col];
        cb[1][cs] = b_ih[256 + col] + b_hh[256 + col];
        bin[cs]   = b_ih[512 + col];
        bhn[cs]   = b_hh[512 + col];
        fcb[cs]   = fc_b[col];
#pragma unroll
        for (int g = 0; g < 3; ++g)
            scq[g][cs] = scales[g * 256 + col] * (1.0f / 16129.0f);   // s/(127*127)
    }
    float ob = (tid < 64) ? out_b[tid & 1] : 0.0f;

    // projection B-frag (bf16 16x16x32): k = wv*32 + qd*8 + j, n = l15 (0,1)
    short8 bproj;
    {
        int k0 = wv * 32 + qd * 8;
#pragma unroll
        for (int j = 0; j < 8; ++j) {
            float v = (l15 == 0) ? out_w[k0 + j] : ((l15 == 1) ? out_w[256 + k0 + j] : 0.0f);
            bproj[j] = (short)f2bf(v);
        }
    }

    __syncthreads();

    // ---- h0 = tanh(z @ fc_w^T + fc_b), bf16 MFMA over K=128 ----
    floatx4 a0f[2][2];
#pragma unroll
    for (int rt = 0; rt < 2; ++rt)
#pragma unroll
        for (int cs = 0; cs < 2; ++cs)
            a0f[rt][cs] = (floatx4){0.f, 0.f, 0.f, 0.f};
#pragma unroll
    for (int kc = 0; kc < 4; ++kc) {
        short8 afr0 = *(const short8*)&h_lds[(0  + l15) * 264 + kc * 32 + qd * 8];
        short8 afr1 = *(const short8*)&h_lds[(16 + l15) * 264 + kc * 32 + qd * 8];
#pragma unroll
        for (int cs = 0; cs < 2; ++cs) {
            short8 bfr = *(const short8*)(ws + FCW_OFF
                            + (size_t)(((wv * 2 + cs) * 4 + kc)) * 1024 + lane * 16);
            a0f[0][cs] = __builtin_amdgcn_mfma_f32_16x16x32_bf16(afr0, bfr, a0f[0][cs], 0, 0, 0);
            a0f[1][cs] = __builtin_amdgcn_mfma_f32_16x16x32_bf16(afr1, bfr, a0f[1][cs], 0, 0, 0);
        }
    }

    float hm0[2][4], hm1[2][4];
#pragma unroll
    for (int cs = 0; cs < 2; ++cs)
#pragma unroll
        for (int r = 0; r < 4; ++r) {
            hm0[cs][r] = tanh_fast(a0f[0][cs][r] + fcb[cs]);
            hm1[cs][r] = tanh_fast(a0f[1][cs][r] + fcb[cs]);
        }

    __syncthreads();   // done reading z
#pragma unroll
    for (int cs = 0; cs < 2; ++cs)
#pragma unroll
        for (int r = 0; r < 4; ++r) {
            int col = wv * 32 + cs * 16 + l15;
            int r0 = qd * 4 + r, r1 = 16 + qd * 4 + r;
            h_lds[r0 * 264 + col] = f2bf(hm0[cs][r]);
            h_lds[r1 * 264 + col] = f2bf(hm1[cs][r]);
            h8[r0 * 272 + col] = (signed char)(int)__builtin_rintf(hm0[cs][r] * 127.0f);
            h8[r1 * 272 + col] = (signed char)(int)__builtin_rintf(hm1[cs][r] * 127.0f);
        }
    __syncthreads();

    // one r-unit: dequant + gates + h update + dual (bf16 + i8) LDS writeback
    auto gate_unit = [&](intx4* a, float (*hmH)[4], int rowbase, int r) {
        float hv[2];
#pragma unroll
        for (int cs = 0; cs < 2; ++cs) {
            float xr = __builtin_fmaf((float)a[cs][r],     scq[0][cs], cb[0][cs]);
            float xz = __builtin_fmaf((float)a[2 + cs][r], scq[1][cs], cb[1][cs]);
            float xn = __builtin_fmaf((float)a[4 + cs][r], scq[2][cs], bhn[cs]);
            float gr = sigmoid_fast(xr);
            float gz = sigmoid_fast(xz);
            float gn = tanh_fast(bin[cs] + gr * xn);
            float h  = gn + gz * (hmH[cs][r] - gn);
            hmH[cs][r] = h;
            hv[cs] = h;
        }
        __hip_bfloat162 pk = __float22bfloat162_rn(make_float2(hv[0], hv[1]));
        union { __hip_bfloat16 b; unsigned short u; } cu0, cu1;
        cu0.b = pk.x; cu1.b = pk.y;
        int row = rowbase + qd * 4 + r;
        int col = wv * 32 + l15;
        h_lds[row * 264 + col]      = cu0.u;
        h_lds[row * 264 + col + 16] = cu1.u;
        h8[row * 272 + col]      = (signed char)(int)__builtin_rintf(hv[0] * 127.0f);
        h8[row * 272 + col + 16] = (signed char)(int)__builtin_rintf(hv[1] * 127.0f);
    };

    // identity-gate init: z-gate acc=1<<22 -> x ~ +60 -> sigma=1 -> h unchanged at t=0
    intx4 acc1[6];
#pragma unroll
    for (int s = 0; s < 6; ++s)
        acc1[s] = (s == 2 || s == 3) ? (intx4){1 << 22, 1 << 22, 1 << 22, 1 << 22}
                                     : (intx4){0, 0, 0, 0};
    intx4 acc0[6];

    // ---- 180 steps, 2 anti-phased slots each ----
#pragma unroll 1
    for (int t = 0; t < T_SEQ; ++t) {
        // ==== SLOT X: i8 MFMA rows0-15 (state t-1) ; gates rows16-31 -> state t ====
        auto mfmaX = [&]() {
#pragma unroll
            for (int s = 0; s < 6; ++s) acc0[s] = (intx4){0, 0, 0, 0};
#pragma unroll
            for (int kc = 0; kc < 4; ++kc) {
                intx4 a8 = *(const intx4*)&h8[l15 * 272 + kc * 64 + qd * 16];
#pragma unroll
                for (int s = 0; s < 6; ++s)
                    acc0[s] = __builtin_amdgcn_mfma_i32_16x16x64_i8(a8, wq[s * 4 + kc], acc0[s], 0, 0, 0);
            }
        };
        auto gatesX = [&]() {
#pragma unroll
            for (int r = 0; r < 4; ++r)
                gate_unit(acc1, hm1, 16, r);      // rows16-31 -> state t
        };
        if (grp == 0) { mfmaX(); gatesX(); }       // wave-uniform branch
        else          { gatesX(); mfmaX(); }       // SIMD partner opposite order
        floatx4 pj0 = (floatx4){0.f, 0.f, 0.f, 0.f};
        {
            short8 afrp = *(const short8*)&h_lds[l15 * 264 + wv * 32 + qd * 8];
            pj0 = __builtin_amdgcn_mfma_f32_16x16x32_bf16(afrp, bproj, pj0, 0, 0, 0);
        }
        if (t >= 2 && tid < 32) {                 // flush bufB: out idx t-2, rows16-31
            int rl = tid >> 1, o = tid & 1;
            float s = ob;
#pragma unroll
            for (int w2 = 0; w2 < 8; ++w2) s += obufw[256 + w2 * 32 + rl * 2 + o];
            out[(size_t)(rb + 16 + rl) * (T_SEQ * 2) + (t - 2) * 2 + o] = s;
        }
        if (t >= 1 && l15 < 2) {                  // per-wave store, no atomics
#pragma unroll
            for (int r = 0; r < 4; ++r)
                obufw[wv * 32 + (qd * 4 + r) * 2 + l15] = pj0[r];
        }
        __syncthreads();

        // ==== SLOT Y: i8 MFMA rows16-31 (state t) ; gates rows0-15 -> state t ====
        auto mfmaY = [&]() {
#pragma unroll
            for (int s = 0; s < 6; ++s) acc1[s] = (intx4){0, 0, 0, 0};
#pragma unroll
            for (int kc = 0; kc < 4; ++kc) {
                intx4 a8 = *(const intx4*)&h8[(16 + l15) * 272 + kc * 64 + qd * 16];
#pragma unroll
                for (int s = 0; s < 6; ++s)
                    acc1[s] = __builtin_amdgcn_mfma_i32_16x16x64_i8(a8, wq[s * 4 + kc], acc1[s], 0, 0, 0);
            }
        };
        auto gatesY = [&]() {
#pragma unroll
            for (int r = 0; r < 4; ++r)
                gate_unit(acc0, hm0, 0, r);       // rows0-15 -> state t
        };
        if (grp == 0) { mfmaY(); gatesY(); }
        else          { gatesY(); mfmaY(); }
        floatx4 pj1 = (floatx4){0.f, 0.f, 0.f, 0.f};
        {
            short8 afrp = *(const short8*)&h_lds[(16 + l15) * 264 + wv * 32 + qd * 8];
            pj1 = __builtin_amdgcn_mfma_f32_16x16x32_bf16(afrp, bproj, pj1, 0, 0, 0);
        }
        if (t >= 1 && tid < 32) {                 // flush bufA: out idx t-1, rows0-15
            int rl = tid >> 1, o = tid & 1;
            float s = ob;
#pragma unroll
            for (int w2 = 0; w2 < 8; ++w2) s += obufw[w2 * 32 + rl * 2 + o];
            out[(size_t)(rb + rl) * (T_SEQ * 2) + (t - 1) * 2 + o] = s;
        }
        if (t >= 1 && l15 < 2) {
#pragma unroll
            for (int r = 0; r < 4; ++r)
                obufw[256 + wv * 32 + (qd * 4 + r) * 2 + l15] = pj1[r];
        }
        __syncthreads();
    }

    // ---- epilogue: finish final rows16-31 state, project final state (out idx 179) ----
#pragma unroll
    for (int r = 0; r < 4; ++r)
        gate_unit(acc1, hm1, 16, r);              // rows16-31 final state
    if (tid < 32) {                               // flush bufB: out idx 178, rows16-31
        int rl = tid >> 1, o = tid & 1;
        float s = ob;
#pragma unroll
        for (int w2 = 0; w2 < 8; ++w2) s += obufw[256 + w2 * 32 + rl * 2 + o];
        out[(size_t)(rb + 16 + rl) * (T_SEQ * 2) + 178 * 2 + o] = s;
    }
    {   // proj of final state rows0-15 (written in last slot Y, barrier passed)
        short8 afrp = *(const short8*)&h_lds[l15 * 264 + wv * 32 + qd * 8];
        floatx4 pj = (floatx4){0.f, 0.f, 0.f, 0.f};
        pj = __builtin_amdgcn_mfma_f32_16x16x32_bf16(afrp, bproj, pj, 0, 0, 0);
        if (l15 < 2)
#pragma unroll
            for (int r = 0; r < 4; ++r)
                obufw[wv * 32 + (qd * 4 + r) * 2 + l15] = pj[r];
    }
    __syncthreads();
    {   // proj of final state rows16-31 (written by gate_units above, barrier passed)
        short8 afrp = *(const short8*)&h_lds[(16 + l15) * 264 + wv * 32 + qd * 8];
        floatx4 pj = (floatx4){0.f, 0.f, 0.f, 0.f};
        pj = __builtin_amdgcn_mfma_f32_16x16x32_bf16(afrp, bproj, pj, 0, 0, 0);
        if (l15 < 2)
#pragma unroll
            for (int r = 0; r < 4; ++r)
                obufw[512 + wv * 32 + (qd * 4 + r) * 2 + l15] = pj[r];
    }
    if (tid < 32) {                               // flush bufA: out idx 179, rows0-15
        int rl = tid >> 1, o = tid & 1;
        float s = ob;
#pragma unroll
        for (int w2 = 0; w2 < 8; ++w2) s += obufw[w2 * 32 + rl * 2 + o];
        out[(size_t)(rb + rl) * (T_SEQ * 2) + 179 * 2 + o] = s;
    }
    __syncthreads();
    if (tid < 32) {                               // flush bufC: out idx 179, rows16-31
        int rl = tid >> 1, o = tid & 1;
        float s = ob;
#pragma unroll
        for (int w2 = 0; w2 < 8; ++w2) s += obufw[512 + w2 * 32 + rl * 2 + o];
        out[(size_t)(rb + 16 + rl) * (T_SEQ * 2) + 179 * 2 + o] = s;
    }
}

extern "C" void kernel_launch(void* const* d_in, const int* in_sizes, int n_in,
                              void* d_out, int out_size, void* d_ws, size_t ws_size,
                              hipStream_t stream) {
    const float* z     = (const float*)d_in[0];
    const float* fc_w  = (const float*)d_in[1];
    const float* fc_b  = (const float*)d_in[2];
    // d_in[3] = w_ih : unused (GRU input is all-zeros, gi = b_ih)
    const float* b_ih  = (const float*)d_in[4];
    const float* w_hh  = (const float*)d_in[5];
    const float* b_hh  = (const float*)d_in[6];
    const float* out_w = (const float*)d_in[7];
    const float* out_b = (const float*)d_in[8];
    float* out = (float*)d_out;
    unsigned char* ws = (unsigned char*)d_ws;   // needs 265,216 B

    hipFuncSetAttribute((const void*)gru_main,
                        hipFuncAttributeMaxDynamicSharedMemorySize, SMEM_BYTES);

    pack_scales<<<192, 256, 0, stream>>>(w_hh, (float*)(ws + SC_OFF));
    pack_whh_i8<<<48, 256, 0, stream>>>(w_hh, (const float*)(ws + SC_OFF),
                                        (signed char*)(ws + WQ_OFF));
    pack_fcw<<<16, 256, 0, stream>>>(fc_w, (unsigned short*)(ws + FCW_OFF));
    gru_main<<<256, 512, SMEM_BYTES, stream>>>(z, fc_b, b_ih, b_hh, out_w, out_b, ws, out);
}

// Round 14
// 535.538 us; speedup vs baseline: 1.3526x; 1.1266x over previous
//
#include <hip/hip_runtime.h>
#include <hip/hip_bf16.h>

#define T_SEQ  180
#define LATENT 128
#define HIDDEN 256

typedef __attribute__((ext_vector_type(8))) short  short8;   // 8 x bf16 (4 VGPRs)
typedef __attribute__((ext_vector_type(4))) float  floatx4;  // f32 MFMA acc
typedef __attribute__((ext_vector_type(4))) int    intx4;    // i8 frag / i32 acc

// ---- d_ws layout (BYTES) ----
#define WQ_OFF    0        // w_hh i8 frags: ((wv*6+sub)*4+kc)*1024, 192 KB
#define FCW_OFF   196608   // fc_w bf16 frags (r9/r13 layout), 64 KB
#define SCW_OFF   262144   // w_hh row scales: float[768]
#define OUTW_OFF  265216   // out_w i8 frags: [slice4][lane64][16B] = 4096 B
#define SWOUT_OFF 269312   // out_w row scales: float[2]

// ---- dynamic LDS layout (bytes) ----
// h8 ping-pong: 2 x 32 rows x 272 B; obuf [pp2][rh2][sl4][16][2] floats
#define H8_STRIDE  272
#define H8B_OFF    8704
#define OBUF_OFF   17408
#define SMEM_BYTES 19456

__device__ __forceinline__ unsigned short f2bf(float f) {
    unsigned int u = __float_as_uint(f);
    u += 0x7fffu + ((u >> 16) & 1u);      // round-to-nearest-even
    return (unsigned short)(u >> 16);
}

__device__ __forceinline__ float sigmoid_fast(float x) {
    return __builtin_amdgcn_rcpf(1.0f + __expf(-x));
}
__device__ __forceinline__ float tanh_fast(float x) {
    return 1.0f - 2.0f * __builtin_amdgcn_rcpf(1.0f + __expf(2.0f * x));
}

// Per-output-unit scales: one wave per row j of w_hh.
__global__ void pack_scales(const float* __restrict__ whh, float* __restrict__ scales) {
    int wid  = blockIdx.x * 4 + (threadIdx.x >> 6);   // 0..767
    int lane = threadIdx.x & 63;
    const float* src = whh + (size_t)wid * 256 + lane * 4;
    float m = 0.0f;
#pragma unroll
    for (int j = 0; j < 4; ++j) m = fmaxf(m, fabsf(src[j]));
#pragma unroll
    for (int d = 1; d < 64; d <<= 1) m = fmaxf(m, __shfl_xor(m, d, 64));
    if (lane == 0) scales[wid] = m;
}

// Pack w_hh [768,256] fp32 -> i8 16x16x64 B-frags (r13-verified layout).
__global__ void pack_whh_i8(const float* __restrict__ whh, const float* __restrict__ scales,
                            signed char* __restrict__ dst) {
    int tid  = blockIdx.x * blockDim.x + threadIdx.x;  // 12288 threads
    int lane = tid & 63;
    int frag = tid >> 6;                               // 0..191
    int kc   = frag & 3;
    int sub  = (frag >> 2) % 6;
    int w    = frag / 24;
    int g = sub >> 1, cs = sub & 1;
    int col  = w * 32 + cs * 16 + (lane & 15);
    int jout = g * 256 + col;
    int k0   = kc * 64 + ((lane >> 4) << 4);
    const float* src = whh + (size_t)jout * 256 + k0;
    float inv = 127.0f / scales[jout];
    signed char q[16];
#pragma unroll
    for (int j = 0; j < 16; ++j) {
        float v = __builtin_rintf(src[j] * inv);
        v = fminf(fmaxf(v, -127.0f), 127.0f);
        q[j] = (signed char)(int)v;
    }
    *(intx4*)(dst + (size_t)frag * 1024 + lane * 16) = *(intx4*)q;
}

// Pack fc_w [256,128] fp32 -> bf16 16x16x32 B-frags (r9 layout).
__global__ void pack_fcw(const float* __restrict__ fcw, unsigned short* __restrict__ dst) {
    int tid  = blockIdx.x * blockDim.x + threadIdx.x;  // 4096 threads
    int lane = tid & 63;
    int frag = tid >> 6;                               // 0..63
    int kc   = frag & 3;
    int cs   = (frag >> 2) & 1;
    int w    = frag >> 3;
    int col  = w * 32 + cs * 16 + (lane & 15);
    int k0   = kc * 32 + ((lane >> 4) << 3);
    const float* src = fcw + col * 128 + k0;
    unsigned int u[4];
#pragma unroll
    for (int j = 0; j < 4; ++j)
        u[j] = (unsigned int)f2bf(src[2 * j]) | ((unsigned int)f2bf(src[2 * j + 1]) << 16);
    *(uint4*)(dst + frag * 512 + lane * 8) = make_uint4(u[0], u[1], u[2], u[3]);
}

// Quantize out_w [2,256] -> i8 proj B-frags [slice4][lane][16B] + row scales.
__global__ void pack_outw_i8(const float* __restrict__ out_w,
                             signed char* __restrict__ dst, float* __restrict__ swout) {
    __shared__ float sw[2];
    int tid = threadIdx.x;
    if (tid < 128) {
        int o = tid >> 6, lane = tid & 63;
        const float* src = out_w + o * 256 + lane * 4;
        float m = 0.0f;
#pragma unroll
        for (int j = 0; j < 4; ++j) m = fmaxf(m, fabsf(src[j]));
#pragma unroll
        for (int d = 1; d < 64; d <<= 1) m = fmaxf(m, __shfl_xor(m, d, 64));
        if (lane == 0) { sw[o] = m; swout[o] = m; }
    }
    __syncthreads();
    int sl = tid >> 6, lane = tid & 63;
    int n  = lane & 15;
    int k0 = sl * 64 + ((lane >> 4) << 4);
    signed char q[16];
#pragma unroll
    for (int j = 0; j < 16; ++j) {
        float v = 0.0f;
        if (n < 2) {
            v = __builtin_rintf(out_w[n * 256 + k0 + j] * (127.0f / sw[n]));
            v = fminf(fmaxf(v, -127.0f), 127.0f);
        }
        q[j] = (signed char)(int)v;
    }
    *(intx4*)(dst + sl * 1024 + lane * 16) = *(intx4*)q;
}

// Persistent GRU r14: monolithic SINGLE-BARRIER step, i8 everywhere.
// 256 blocks x 512 thr, 32 rows/block, wave owns 32 cols. All 3 gates' i8
// weights in regs (wq[24]=96 VGPR, r13-proven). h exists ONLY as i8 in a
// ping-pong LDS pair; projection is i8 MFMA vs per-row-quantized out_w
// (wave w: row-half w>>2, 64-col slice w&3). One barrier/step (overlap is
// falsified r7-r10 -> 2-slot structure only cost a 2nd barrier drain).
__global__ __launch_bounds__(512, 2) void gru_main(
    const float* __restrict__ z,
    const float* __restrict__ fc_b,
    const float* __restrict__ b_ih,
    const float* __restrict__ b_hh,
    const float* __restrict__ out_b,
    const unsigned char* __restrict__ ws,
    float* __restrict__ out)
{
    extern __shared__ unsigned char smem[];
    signed char* h8a  = (signed char*)smem;                 // buf0
    signed char* h8b  = (signed char*)(smem + H8B_OFF);     // buf1
    float*       obuf = (float*)(smem + OBUF_OFF);          // [2][2][4][16][2]

    const int tid  = threadIdx.x;
    const int lane = tid & 63;
    const int wv   = tid >> 6;
    const int l15  = lane & 15;
    const int qd   = lane >> 4;
    const int rh   = wv >> 2;        // proj row-half
    const int sl   = wv & 3;         // proj 64-col slice
    const int rb   = blockIdx.x * 32;

    // ---- all 3 gates' i8 weight frags into registers (96 VGPRs) ----
    intx4 wq[24];
#pragma unroll
    for (int sub = 0; sub < 6; ++sub)
#pragma unroll
        for (int kc = 0; kc < 4; ++kc)
            wq[sub * 4 + kc] = *(const intx4*)(ws + WQ_OFF
                                + (size_t)((wv * 6 + sub) * 4 + kc) * 1024 + lane * 16);

    // ---- proj B-frag (i8) + per-lane constants ----
    intx4 bproj = *(const intx4*)(ws + OUTW_OFF + sl * 1024 + lane * 16);
    const float* swout = (const float*)(ws + SWOUT_OFF);
    float psc = (l15 < 2) ? swout[l15] * (1.0f / 16129.0f) : 0.0f;

    const float* scales = (const float*)(ws + SCW_OFF);
    float cbr[2], cbz[2], bhn[2], bin[2], fcb[2], scq[3][2];
#pragma unroll
    for (int cs = 0; cs < 2; ++cs) {
        int col = wv * 32 + cs * 16 + l15;
        cbr[cs] = b_ih[col]       + b_hh[col];
        cbz[cs] = b_ih[256 + col] + b_hh[256 + col];
        bin[cs] = b_ih[512 + col];
        bhn[cs] = b_hh[512 + col];
        fcb[cs] = fc_b[col];
#pragma unroll
        for (int g = 0; g < 3; ++g)
            scq[g][cs] = scales[g * 256 + col] * (1.0f / 16129.0f);
    }
    float ob = (tid < 64) ? out_b[tid & 1] : 0.0f;

    // ---- h0 = tanh(z @ fc_w^T + fc_b): bf16 MFMA, A-frags direct from global ----
    floatx4 a0f[2][2];
#pragma unroll
    for (int rt = 0; rt < 2; ++rt)
#pragma unroll
        for (int cs = 0; cs < 2; ++cs)
            a0f[rt][cs] = (floatx4){0.f, 0.f, 0.f, 0.f};
#pragma unroll
    for (int kc = 0; kc < 4; ++kc) {
#pragma unroll
        for (int rt = 0; rt < 2; ++rt) {
            const float* zp = z + (size_t)(rb + rt * 16 + l15) * LATENT + kc * 32 + qd * 8;
            short8 afr;
#pragma unroll
            for (int j = 0; j < 8; ++j) afr[j] = (short)f2bf(zp[j]);
#pragma unroll
            for (int cs = 0; cs < 2; ++cs) {
                short8 bfr = *(const short8*)(ws + FCW_OFF
                                + (size_t)((wv * 2 + cs) * 4 + kc) * 1024 + lane * 16);
                a0f[rt][cs] = __builtin_amdgcn_mfma_f32_16x16x32_bf16(afr, bfr, a0f[rt][cs], 0, 0, 0);
            }
        }
    }

    // master h fp32 in regs; write h0 (i8) to buf0
    float hm[2][2][4];
#pragma unroll
    for (int rt = 0; rt < 2; ++rt)
#pragma unroll
        for (int cs = 0; cs < 2; ++cs)
#pragma unroll
            for (int r = 0; r < 4; ++r) {
                float h = tanh_fast(a0f[rt][cs][r] + fcb[cs]);
                hm[rt][cs][r] = h;
                h8a[(rt * 16 + qd * 4 + r) * H8_STRIDE + wv * 32 + cs * 16 + l15] =
                    (signed char)(int)__builtin_rintf(h * 127.0f);
            }
    __syncthreads();

    // ---- 180 monolithic steps, ONE barrier each ----
#pragma unroll 1
    for (int t = 0; t < T_SEQ; ++t) {
        const int p = t & 1;
        signed char* h8p = p ? h8b : h8a;       // read: state s_t
        signed char* h8n = p ? h8a : h8b;       // write: state s_{t+1}

        // gate MFMAs: 48 i8 (2 row-tiles x 6 acc x 4 kc)
        intx4 acc[2][6];
#pragma unroll
        for (int rt = 0; rt < 2; ++rt)
#pragma unroll
            for (int s = 0; s < 6; ++s) acc[rt][s] = (intx4){0, 0, 0, 0};
#pragma unroll
        for (int kc = 0; kc < 4; ++kc) {
            intx4 a80 = *(const intx4*)&h8p[(0  + l15) * H8_STRIDE + kc * 64 + qd * 16];
            intx4 a81 = *(const intx4*)&h8p[(16 + l15) * H8_STRIDE + kc * 64 + qd * 16];
#pragma unroll
            for (int s = 0; s < 6; ++s) {
                acc[0][s] = __builtin_amdgcn_mfma_i32_16x16x64_i8(a80, wq[s * 4 + kc], acc[0][s], 0, 0, 0);
                acc[1][s] = __builtin_amdgcn_mfma_i32_16x16x64_i8(a81, wq[s * 4 + kc], acc[1][s], 0, 0, 0);
            }
        }

        // proj of s_t (out idx t-1): wave's (row-half, 64-col slice), i8 MFMA
        intx4 pj = (intx4){0, 0, 0, 0};
        {
            intx4 a8p = *(const intx4*)&h8p[(rh * 16 + l15) * H8_STRIDE + sl * 64 + qd * 16];
            pj = __builtin_amdgcn_mfma_i32_16x16x64_i8(a8p, bproj, pj, 0, 0, 0);
        }

        // flush obuf written at step t-1 (out idx t-2)
        if (t >= 2 && tid < 64) {
            int rl = tid >> 1, o = tid & 1;
            int frh = rl >> 4, fr = rl & 15;
            int base = ((p ^ 1) * 2 + frh) * 128 + fr * 2 + o;
            float s = ob + obuf[base] + obuf[base + 32] + obuf[base + 64] + obuf[base + 96];
            out[(size_t)(rb + rl) * (T_SEQ * 2) + (t - 2) * 2 + o] = s;
        }

        // gates -> s_{t+1}, write h8 next buffer
#pragma unroll
        for (int rt = 0; rt < 2; ++rt)
#pragma unroll
            for (int cs = 0; cs < 2; ++cs)
#pragma unroll
                for (int r = 0; r < 4; ++r) {
                    float xr = __builtin_fmaf((float)acc[rt][cs][r],     scq[0][cs], cbr[cs]);
                    float xz = __builtin_fmaf((float)acc[rt][2 + cs][r], scq[1][cs], cbz[cs]);
                    float xn = __builtin_fmaf((float)acc[rt][4 + cs][r], scq[2][cs], bhn[cs]);
                    float gr = sigmoid_fast(xr);
                    float gz = sigmoid_fast(xz);
                    float gn = tanh_fast(bin[cs] + gr * xn);
                    float h  = gn + gz * (hm[rt][cs][r] - gn);
                    hm[rt][cs][r] = h;
                    h8n[(rt * 16 + qd * 4 + r) * H8_STRIDE + wv * 32 + cs * 16 + l15] =
                        (signed char)(int)__builtin_rintf(h * 127.0f);
                }

        // stash proj partials (out idx t-1) into obuf[p]
        if (t >= 1 && l15 < 2) {
#pragma unroll
            for (int r = 0; r < 4; ++r)
                obuf[(p * 2 + rh) * 128 + sl * 32 + (qd * 4 + r) * 2 + l15] = (float)pj[r] * psc;
        }

        __syncthreads();   // the single per-step barrier
    }

    // ---- epilogue ----
    if (tid < 64) {        // flush obuf[1] (written at t=179): out idx 178
        int rl = tid >> 1, o = tid & 1;
        int frh = rl >> 4, fr = rl & 15;
        int base = (1 * 2 + frh) * 128 + fr * 2 + o;
        float s = ob + obuf[base] + obuf[base + 32] + obuf[base + 64] + obuf[base + 96];
        out[(size_t)(rb + rl) * (T_SEQ * 2) + 178 * 2 + o] = s;
    }
    {   // proj of s_180 (in buf0 after step 179): out idx 179 -> obuf[0]
        intx4 a8p = *(const intx4*)&h8a[(rh * 16 + l15) * H8_STRIDE + sl * 64 + qd * 16];
        intx4 pj = (intx4){0, 0, 0, 0};
        pj = __builtin_amdgcn_mfma_i32_16x16x64_i8(a8p, bproj, pj, 0, 0, 0);
        if (l15 < 2)
#pragma unroll
            for (int r = 0; r < 4; ++r)
                obuf[(0 * 2 + rh) * 128 + sl * 32 + (qd * 4 + r) * 2 + l15] = (float)pj[r] * psc;
    }
    __syncthreads();
    if (tid < 64) {        // flush obuf[0]: out idx 179
        int rl = tid >> 1, o = tid & 1;
        int frh = rl >> 4, fr = rl & 15;
        int base = (0 * 2 + frh) * 128 + fr * 2 + o;
        float s = ob + obuf[base] + obuf[base + 32] + obuf[base + 64] + obuf[base + 96];
        out[(size_t)(rb + rl) * (T_SEQ * 2) + 179 * 2 + o] = s;
    }
}

extern "C" void kernel_launch(void* const* d_in, const int* in_sizes, int n_in,
                              void* d_out, int out_size, void* d_ws, size_t ws_size,
                              hipStream_t stream) {
    const float* z     = (const float*)d_in[0];
    const float* fc_w  = (const float*)d_in[1];
    const float* fc_b  = (const float*)d_in[2];
    // d_in[3] = w_ih : unused (GRU input is all-zeros, gi = b_ih)
    const float* b_ih  = (const float*)d_in[4];
    const float* w_hh  = (const float*)d_in[5];
    const float* b_hh  = (const float*)d_in[6];
    const float* out_w = (const float*)d_in[7];
    const float* out_b = (const float*)d_in[8];
    float* out = (float*)d_out;
    unsigned char* ws = (unsigned char*)d_ws;   // needs 269,320 B

    hipFuncSetAttribute((const void*)gru_main,
                        hipFuncAttributeMaxDynamicSharedMemorySize, SMEM_BYTES);

    pack_scales<<<192, 256, 0, stream>>>(w_hh, (float*)(ws + SCW_OFF));
    pack_whh_i8<<<48, 256, 0, stream>>>(w_hh, (const float*)(ws + SCW_OFF),
                                        (signed char*)(ws + WQ_OFF));
    pack_fcw<<<16, 256, 0, stream>>>(fc_w, (unsigned short*)(ws + FCW_OFF));
    pack_outw_i8<<<1, 256, 0, stream>>>(out_w, (signed char*)(ws + OUTW_OFF),
                                        (float*)(ws + SWOUT_OFF));
    gru_main<<<256, 512, SMEM_BYTES, stream>>>(z, fc_b, b_ih, b_hh, out_b, ws, out);
}

// Round 16
// 512.568 us; speedup vs baseline: 1.4133x; 1.0448x over previous
//
#include <hip/hip_runtime.h>
#include <hip/hip_bf16.h>

#define T_SEQ  180
#define LATENT 128
#define HIDDEN 256

typedef __attribute__((ext_vector_type(8))) short  short8;   // 8 x bf16 (4 VGPRs)
typedef __attribute__((ext_vector_type(4))) float  floatx4;  // f32 MFMA acc
typedef __attribute__((ext_vector_type(4))) int    intx4;    // i8 frag / i32 acc

#define LOG2E 1.4426950408889634f

// ---- d_ws layout (BYTES) ----
#define WQ_OFF    0        // w_hh i8 frags: ((wv*6+sub)*4+kc)*1024, 192 KB
#define FCW_OFF   196608   // fc_w bf16 frags (r9/r13 layout), 64 KB
#define SCW_OFF   262144   // w_hh row scales: float[768]
#define OUTW_OFF  265216   // out_w i8 frags: [slice4][lane64][16B] = 4096 B
#define SWOUT_OFF 269312   // out_w row scales: float[2]

// ---- dynamic LDS layout (bytes) ----
// [0,     65536) : n-gate i8 frags: (wv*8 + s2*4 + kc)*1024
// [65536, 74240) : h8 ping-pong: 2 x 16 rows x 272 B
// [74240, 75264) : obuf [pp2][sl4][16][2] float
#define H8A_OFF    65536
#define H8B_OFF    69888
#define OBUF_OFF   74240
#define SMEM_BYTES 75264
#define H8_STRIDE  272

__device__ __forceinline__ unsigned short f2bf(float f) {
    unsigned int u = __float_as_uint(f);
    u += 0x7fffu + ((u >> 16) & 1u);      // round-to-nearest-even
    return (unsigned short)(u >> 16);
}

// exp2-form nonlinearities (log2e pre-folded into the operand by caller)
__device__ __forceinline__ float sig_e2(float ylog2e) {       // sigma(x), y = x*log2e
    return __builtin_amdgcn_rcpf(1.0f + __builtin_amdgcn_exp2f(-ylog2e));
}
__device__ __forceinline__ float tanh_e2(float y2log2e) {     // tanh(x), y = 2x*log2e
    return __builtin_fmaf(-2.0f,
        __builtin_amdgcn_rcpf(1.0f + __builtin_amdgcn_exp2f(y2log2e)), 1.0f);
}

// Per-output-unit scales: one wave per row j of w_hh.
__global__ void pack_scales(const float* __restrict__ whh, float* __restrict__ scales) {
    int wid  = blockIdx.x * 4 + (threadIdx.x >> 6);   // 0..767
    int lane = threadIdx.x & 63;
    const float* src = whh + (size_t)wid * 256 + lane * 4;
    float m = 0.0f;
#pragma unroll
    for (int j = 0; j < 4; ++j) m = fmaxf(m, fabsf(src[j]));
#pragma unroll
    for (int d = 1; d < 64; d <<= 1) m = fmaxf(m, __shfl_xor(m, d, 64));
    if (lane == 0) scales[wid] = m;
}

// Pack w_hh [768,256] fp32 -> i8 16x16x64 B-frags (r13-verified layout).
__global__ void pack_whh_i8(const float* __restrict__ whh, const float* __restrict__ scales,
                            signed char* __restrict__ dst) {
    int tid  = blockIdx.x * blockDim.x + threadIdx.x;  // 12288 threads
    int lane = tid & 63;
    int frag = tid >> 6;                               // 0..191
    int kc   = frag & 3;
    int sub  = (frag >> 2) % 6;
    int w    = frag / 24;
    int g = sub >> 1, cs = sub & 1;
    int col  = w * 32 + cs * 16 + (lane & 15);
    int jout = g * 256 + col;
    int k0   = kc * 64 + ((lane >> 4) << 4);
    const float* src = whh + (size_t)jout * 256 + k0;
    float inv = 127.0f / scales[jout];
    signed char q[16];
#pragma unroll
    for (int j = 0; j < 16; ++j) {
        float v = __builtin_rintf(src[j] * inv);
        v = fminf(fmaxf(v, -127.0f), 127.0f);
        q[j] = (signed char)(int)v;
    }
    *(intx4*)(dst + (size_t)frag * 1024 + lane * 16) = *(intx4*)q;
}

// Pack fc_w [256,128] fp32 -> bf16 16x16x32 B-frags (r9 layout).
__global__ void pack_fcw(const float* __restrict__ fcw, unsigned short* __restrict__ dst) {
    int tid  = blockIdx.x * blockDim.x + threadIdx.x;  // 4096 threads
    int lane = tid & 63;
    int frag = tid >> 6;                               // 0..63
    int kc   = frag & 3;
    int cs   = (frag >> 2) & 1;
    int w    = frag >> 3;
    int col  = w * 32 + cs * 16 + (lane & 15);
    int k0   = kc * 32 + ((lane >> 4) << 3);
    const float* src = fcw + col * 128 + k0;
    unsigned int u[4];
#pragma unroll
    for (int j = 0; j < 4; ++j)
        u[j] = (unsigned int)f2bf(src[2 * j]) | ((unsigned int)f2bf(src[2 * j + 1]) << 16);
    *(uint4*)(dst + frag * 512 + lane * 8) = make_uint4(u[0], u[1], u[2], u[3]);
}

// Quantize out_w [2,256] -> i8 proj B-frags [slice4][lane][16B] + row scales.
__global__ void pack_outw_i8(const float* __restrict__ out_w,
                             signed char* __restrict__ dst, float* __restrict__ swout) {
    __shared__ float sw[2];
    int tid = threadIdx.x;
    if (tid < 128) {
        int o = tid >> 6, lane = tid & 63;
        const float* src = out_w + o * 256 + lane * 4;
        float m = 0.0f;
#pragma unroll
        for (int j = 0; j < 4; ++j) m = fmaxf(m, fabsf(src[j]));
#pragma unroll
        for (int d = 1; d < 64; d <<= 1) m = fmaxf(m, __shfl_xor(m, d, 64));
        if (lane == 0) { sw[o] = m; swout[o] = m; }
    }
    __syncthreads();
    int sl = tid >> 6, lane = tid & 63;
    int n  = lane & 15;
    int k0 = sl * 64 + ((lane >> 4) << 4);
    signed char q[16];
#pragma unroll
    for (int j = 0; j < 16; ++j) {
        float v = 0.0f;
        if (n < 2) {
            v = __builtin_rintf(out_w[n * 256 + k0 + j] * (127.0f / sw[n]));
            v = fminf(fmaxf(v, -127.0f), 127.0f);
        }
        q[j] = (signed char)(int)v;
    }
    *(intx4*)(dst + sl * 1024 + lane * 16) = *(intx4*)q;
}

// Persistent GRU r16 = r15 + ob fix (r15's in-loop flush threads had ob=0 --
// absmax 0.168 = max|out_b|, architecture untested). 512 blocks x 512 thr,
// 16 rows/block, 2 BLOCKS/CU: independent per-block barriers let the two
// blocks' MFMA and VALU phases interleave on shared pipes (m114 via
// occupancy -- intra-block overlap falsified r7-r10). Budget 128 VGPR
// (4 waves/SIMD): r,z i8 frags in regs (64 VGPR), n-gate in LDS. i8
// everywhere (r14); log2e folded into scales (exp2-form nonlinearities).
__global__ __launch_bounds__(512, 4) void gru_main(
    const float* __restrict__ z,
    const float* __restrict__ fc_b,
    const float* __restrict__ b_ih,
    const float* __restrict__ b_hh,
    const float* __restrict__ out_b,
    const unsigned char* __restrict__ ws,
    float* __restrict__ out)
{
    extern __shared__ unsigned char smem[];
    signed char* wlds = (signed char*)smem;                 // n-gate frags
    signed char* h8a  = (signed char*)(smem + H8A_OFF);
    signed char* h8b  = (signed char*)(smem + H8B_OFF);
    float*       obuf = (float*)(smem + OBUF_OFF);          // [2][4][16][2]

    const int tid  = threadIdx.x;
    const int lane = tid & 63;
    const int wv   = tid >> 6;
    const int l15  = lane & 15;
    const int qd   = lane >> 4;
    const int rb   = blockIdx.x * 16;

    // ---- stage n-gate i8 frags into LDS (8 KB per wave) ----
#pragma unroll
    for (int s2 = 0; s2 < 2; ++s2)
#pragma unroll
        for (int kc = 0; kc < 4; ++kc) {
            int gfrag = (wv * 6 + 4 + s2) * 4 + kc;
            intx4 v = *(const intx4*)(ws + WQ_OFF + (size_t)gfrag * 1024 + lane * 16);
            *(intx4*)(wlds + (wv * 8 + s2 * 4 + kc) * 1024 + lane * 16) = v;
        }

    // ---- r,z-gate i8 frags into registers (16 frags = 64 VGPRs) ----
    intx4 wq[16];
#pragma unroll
    for (int sub = 0; sub < 4; ++sub)
#pragma unroll
        for (int kc = 0; kc < 4; ++kc)
            wq[sub * 4 + kc] = *(const intx4*)(ws + WQ_OFF
                                + (size_t)((wv * 6 + sub) * 4 + kc) * 1024 + lane * 16);

    // ---- proj B-frag (i8, waves 0-3 only) + per-lane constants ----
    intx4 bproj = *(const intx4*)(ws + OUTW_OFF + (wv & 3) * 1024 + lane * 16);
    const float* swout = (const float*)(ws + SWOUT_OFF);
    float psc = (l15 < 2) ? swout[l15] * (1.0f / 16129.0f) : 0.0f;

    const float* scales = (const float*)(ws + SCW_OFF);
    float cbrE[2], cbzE[2], bhnE2[2], binE2[2], fcbE2[2];
    float scqrE[2], scqzE[2], scqnE2[2];
#pragma unroll
    for (int cs = 0; cs < 2; ++cs) {
        int col = wv * 32 + cs * 16 + l15;
        cbrE[cs]  = (b_ih[col]       + b_hh[col])       * LOG2E;
        cbzE[cs]  = (b_ih[256 + col] + b_hh[256 + col]) * LOG2E;
        binE2[cs] = b_ih[512 + col] * (2.0f * LOG2E);
        bhnE2[cs] = b_hh[512 + col] * (2.0f * LOG2E);
        fcbE2[cs] = fc_b[col] * (2.0f * LOG2E);
        float s0 = scales[col]       * (1.0f / 16129.0f);
        float s1 = scales[256 + col] * (1.0f / 16129.0f);
        float s2 = scales[512 + col] * (1.0f / 16129.0f);
        scqrE[cs]  = s0 * LOG2E;
        scqzE[cs]  = s1 * LOG2E;
        scqnE2[cs] = s2 * (2.0f * LOG2E);
    }
    // r16 FIX: every thread loads the correct output bias (r15 zeroed it for
    // the in-loop flush threads tid>=256 -> absmax = max|out_b|).
    float ob = out_b[tid & 1];

    // ---- h0 = tanh(z @ fc_w^T + fc_b): bf16 MFMA, A-frags direct from global ----
    floatx4 a0f[2];
#pragma unroll
    for (int cs = 0; cs < 2; ++cs) a0f[cs] = (floatx4){0.f, 0.f, 0.f, 0.f};
#pragma unroll
    for (int kc = 0; kc < 4; ++kc) {
        const float* zp = z + (size_t)(rb + l15) * LATENT + kc * 32 + qd * 8;
        short8 afr;
#pragma unroll
        for (int j = 0; j < 8; ++j) afr[j] = (short)f2bf(zp[j]);
#pragma unroll
        for (int cs = 0; cs < 2; ++cs) {
            short8 bfr = *(const short8*)(ws + FCW_OFF
                            + (size_t)((wv * 2 + cs) * 4 + kc) * 1024 + lane * 16);
            a0f[cs] = __builtin_amdgcn_mfma_f32_16x16x32_bf16(afr, bfr, a0f[cs], 0, 0, 0);
        }
    }

    float hm[2][4];
#pragma unroll
    for (int cs = 0; cs < 2; ++cs)
#pragma unroll
        for (int r = 0; r < 4; ++r) {
            float h = tanh_e2(__builtin_fmaf(a0f[cs][r], 2.0f * LOG2E, fcbE2[cs]));
            hm[cs][r] = h;
            h8a[(qd * 4 + r) * H8_STRIDE + wv * 32 + cs * 16 + l15] =
                (signed char)(int)__builtin_rintf(h * 127.0f);
        }
    __syncthreads();

    // ---- 180 monolithic steps, ONE barrier each ----
#pragma unroll 1
    for (int t = 0; t < T_SEQ; ++t) {
        const int p = t & 1;
        signed char* h8p = p ? h8b : h8a;       // read: state s_t
        signed char* h8n = p ? h8a : h8b;       // write: state s_{t+1}

        // gate MFMAs: 24 i8 (6 acc x 4 kc); r,z B from regs, n B from LDS
        intx4 acc[6];
#pragma unroll
        for (int s = 0; s < 6; ++s) acc[s] = (intx4){0, 0, 0, 0};
#pragma unroll
        for (int kc = 0; kc < 4; ++kc) {
            intx4 a8 = *(const intx4*)&h8p[l15 * H8_STRIDE + kc * 64 + qd * 16];
#pragma unroll
            for (int s = 0; s < 4; ++s)
                acc[s] = __builtin_amdgcn_mfma_i32_16x16x64_i8(a8, wq[s * 4 + kc], acc[s], 0, 0, 0);
            intx4 bn0 = *(const intx4*)(wlds + (wv * 8 + 0 + kc) * 1024 + lane * 16);
            intx4 bn1 = *(const intx4*)(wlds + (wv * 8 + 4 + kc) * 1024 + lane * 16);
            acc[4] = __builtin_amdgcn_mfma_i32_16x16x64_i8(a8, bn0, acc[4], 0, 0, 0);
            acc[5] = __builtin_amdgcn_mfma_i32_16x16x64_i8(a8, bn1, acc[5], 0, 0, 0);
        }

        // proj of s_t (out idx t-1): waves 0-3, 64-col k-slice each
        intx4 pj = (intx4){0, 0, 0, 0};
        if (wv < 4) {
            intx4 a8p = *(const intx4*)&h8p[l15 * H8_STRIDE + (wv & 3) * 64 + qd * 16];
            pj = __builtin_amdgcn_mfma_i32_16x16x64_i8(a8p, bproj, pj, 0, 0, 0);
        }

        // flush obuf written at step t-1 (out idx t-2); wave 4 owns this
        if (t >= 2 && tid >= 256 && tid < 288) {
            int rl = (tid - 256) >> 1, o = tid & 1;
            int base = (p ^ 1) * 128 + rl * 2 + o;
            float s = ob + obuf[base] + obuf[base + 32] + obuf[base + 64] + obuf[base + 96];
            out[(size_t)(rb + rl) * (T_SEQ * 2) + (t - 2) * 2 + o] = s;
        }

        // gates -> s_{t+1} (exp2-form, log2e pre-folded), write h8 next buffer
#pragma unroll
        for (int cs = 0; cs < 2; ++cs)
#pragma unroll
            for (int r = 0; r < 4; ++r) {
                float yr  = __builtin_fmaf((float)acc[cs][r],     scqrE[cs],  cbrE[cs]);
                float yz  = __builtin_fmaf((float)acc[2 + cs][r], scqzE[cs],  cbzE[cs]);
                float xn2 = __builtin_fmaf((float)acc[4 + cs][r], scqnE2[cs], bhnE2[cs]);
                float gr = sig_e2(yr);
                float gz = sig_e2(yz);
                float gn = tanh_e2(__builtin_fmaf(gr, xn2, binE2[cs]));
                float h  = __builtin_fmaf(gz, hm[cs][r] - gn, gn);
                hm[cs][r] = h;
                h8n[(qd * 4 + r) * H8_STRIDE + wv * 32 + cs * 16 + l15] =
                    (signed char)(int)__builtin_rintf(h * 127.0f);
            }

        // stash proj partials (out idx t-1) into obuf[p]
        if (t >= 1 && wv < 4 && l15 < 2) {
#pragma unroll
            for (int r = 0; r < 4; ++r)
                obuf[p * 128 + (wv & 3) * 32 + (qd * 4 + r) * 2 + l15] = (float)pj[r] * psc;
        }

        __syncthreads();   // the single per-step barrier
    }

    // ---- epilogue ----
    if (tid < 32) {        // flush obuf[1] (stashed at t=179): out idx 178
        int rl = tid >> 1, o = tid & 1;
        int base = 128 + rl * 2 + o;
        float s = ob + obuf[base] + obuf[base + 32] + obuf[base + 64] + obuf[base + 96];
        out[(size_t)(rb + rl) * (T_SEQ * 2) + 178 * 2 + o] = s;
    }
    if (wv < 4) {          // proj of s_180 (in h8a after step 179) -> obuf[0]
        intx4 a8p = *(const intx4*)&h8a[l15 * H8_STRIDE + (wv & 3) * 64 + qd * 16];
        intx4 pj = (intx4){0, 0, 0, 0};
        pj = __builtin_amdgcn_mfma_i32_16x16x64_i8(a8p, bproj, pj, 0, 0, 0);
        if (l15 < 2)
#pragma unroll
            for (int r = 0; r < 4; ++r)
                obuf[(wv & 3) * 32 + (qd * 4 + r) * 2 + l15] = (float)pj[r] * psc;
    }
    __syncthreads();
    if (tid < 32) {        // flush obuf[0]: out idx 179
        int rl = tid >> 1, o = tid & 1;
        int base = rl * 2 + o;
        float s = ob + obuf[base] + obuf[base + 32] + obuf[base + 64] + obuf[base + 96];
        out[(size_t)(rb + rl) * (T_SEQ * 2) + 179 * 2 + o] = s;
    }
}

extern "C" void kernel_launch(void* const* d_in, const int* in_sizes, int n_in,
                              void* d_out, int out_size, void* d_ws, size_t ws_size,
                              hipStream_t stream) {
    const float* z     = (const float*)d_in[0];
    const float* fc_w  = (const float*)d_in[1];
    const float* fc_b  = (const float*)d_in[2];
    // d_in[3] = w_ih : unused (GRU input is all-zeros, gi = b_ih)
    const float* b_ih  = (const float*)d_in[4];
    const float* w_hh  = (const float*)d_in[5];
    const float* b_hh  = (const float*)d_in[6];
    const float* out_w = (const float*)d_in[7];
    const float* out_b = (const float*)d_in[8];
    float* out = (float*)d_out;
    unsigned char* ws = (unsigned char*)d_ws;   // needs 269,320 B

    hipFuncSetAttribute((const void*)gru_main,
                        hipFuncAttributeMaxDynamicSharedMemorySize, SMEM_BYTES);

    pack_scales<<<192, 256, 0, stream>>>(w_hh, (float*)(ws + SCW_OFF));
    pack_whh_i8<<<48, 256, 0, stream>>>(w_hh, (const float*)(ws + SCW_OFF),
                                        (signed char*)(ws + WQ_OFF));
    pack_fcw<<<16, 256, 0, stream>>>(fc_w, (unsigned short*)(ws + FCW_OFF));
    pack_outw_i8<<<1, 256, 0, stream>>>(out_w, (signed char*)(ws + OUTW_OFF),
                                        (float*)(ws + SWOUT_OFF));
    gru_main<<<512, 512, SMEM_BYTES, stream>>>(z, fc_b, b_ih, b_hh, out_b, ws, out);
}